// Round 1
// 572.485 us; speedup vs baseline: 1.0537x; 1.0537x over previous
//
#include <hip/hip_runtime.h>

#define B_ 16
#define NQ 2048
#define NK 2048
#define DH 128
#define INV 0.08838834764831843f   // 1/sqrt(128)

typedef __attribute__((ext_vector_type(8))) short bf16x8;
typedef __attribute__((ext_vector_type(4))) float f32x4;

typedef const __attribute__((address_space(1))) unsigned int* gas1_t;
typedef __attribute__((address_space(3))) unsigned int* las3_t;

__device__ __forceinline__ unsigned short f2b(float f) {
  unsigned u = __float_as_uint(f);
  u += 0x7fff + ((u >> 16) & 1);          // RNE
  return (unsigned short)(u >> 16);
}

// async 16B global->LDS (DMA, no VGPR roundtrip). LDS dest must be
// wave-uniform-base + lane*16; source is per-lane (pre-swizzled).
__device__ __forceinline__ void gl_lds16(const unsigned short* g, unsigned short* l) {
  __builtin_amdgcn_global_load_lds((gas1_t)g, (las3_t)l, 16, 0, 0);
}

// ---------------- prep: fp32 -> bf16 cast (q, k) ----------------------------
__global__ __launch_bounds__(256) void k_cvt(
    const float* __restrict__ src, unsigned short* __restrict__ dst, int n4) {
  int i = blockIdx.x * 256 + threadIdx.x;
  if (i >= n4) return;
  float4 f = ((const float4*)src)[i];
  ushort4 u;
  u.x = f2b(f.x); u.y = f2b(f.y); u.z = f2b(f.z); u.w = f2b(f.w);
  ((ushort4*)dst)[i] = u;
}

// ---------------- prep: V [b][kv][d] -> Vt bf16 [b][d][kv] ------------------
__global__ __launch_bounds__(256) void k_trans(
    const float* __restrict__ v, unsigned short* __restrict__ vt) {
  __shared__ float tile[32][33];
  const int b = blockIdx.z, kv0 = blockIdx.x << 5, d0 = blockIdx.y << 5;
  const int tx = threadIdx.x & 31, ty = threadIdx.x >> 5;
  #pragma unroll
  for (int i = 0; i < 4; i++)
    tile[ty + 8*i][tx] = v[((size_t)b*NK + kv0 + ty + 8*i)*DH + d0 + tx];
  __syncthreads();
  #pragma unroll
  for (int i = 0; i < 4; i++)
    vt[((size_t)b*DH + d0 + ty + 8*i)*NK + kv0 + tx] = f2b(tile[tx][ty + 8*i]);
}

// ---------------- fused attention -------------------------------------------
// Block: 256 thr = 4 waves; 32 q-rows; K swept in 64-col tiles (32 tiles).
// Wave (rh,nh): rh = q-row half (16 rows), nh = k-col half (32 cols).
// Sweep1: S=QK^T, row sumexp; mask read ONCE (nontemporal), bits kept in a
//         per-lane 256-bit register shift queue (8 u32) - no LDS bitboard.
// Sweep2: recompute S, att=exp(s)*il (nontemporal store), P->LDS bf16, P@Vt.
// Staging: global_load_lds, linear LDS, XOR-swizzled source+reads (no pads).
// Sync: raw s_barrier + counted vmcnt (loads stay in flight across barriers).
__global__ __launch_bounds__(256, 4) void k_attn(
    const unsigned short* __restrict__ qb, const unsigned short* __restrict__ kb,
    const unsigned short* __restrict__ vtb, const int* __restrict__ mask,
    float* __restrict__ att, float* __restrict__ ctx) {
  __shared__ unsigned short KA[64*128];   // 16KB: sweep1 K buf0 / sweep2 K
  __shared__ unsigned short VA[128*64];   // 16KB: sweep1 K buf1 / sweep2 Vt[d][kv]
  __shared__ unsigned short Ps[32*64];    // 4KB
  __shared__ float Lrow[32];              // total 36992 B -> 4 blocks/CU

  const int t = threadIdx.x;
  const int wave = t >> 6, lane = t & 63, quad = lane >> 4, l15 = lane & 15;
  const int rh = wave >> 1, nh = wave & 1;

  // XCD-aware swizzle over 1024 blocks (1024%8==0 -> bijective). Each XCD
  // gets 2 consecutive batches -> K/Vt (~3MB) stays L2-resident for sweep2.
  const int p = blockIdx.x + (blockIdx.y << 6);
  const int lid = ((p & 7) << 7) + (p >> 3);
  const int b = lid >> 6, q0 = (lid & 63) << 5;

  const unsigned short* qg = qb  + ((size_t)b*NQ + q0)*DH;
  const unsigned short* kg = kb  + (size_t)b*NK*DH;
  const unsigned short* vg = vtb + (size_t)b*DH*NK;
  const int* mg   = mask + ((size_t)b*NQ + q0)*NK;
  float*     attg = att  + ((size_t)b*NQ + q0)*NK;
  float*     cg   = ctx  + ((size_t)b*NQ + q0)*DH;

  if (t < 32) Lrow[t] = 0.f;

  // ---- Q fragments hoisted to registers (16 VGPR, loaded once) ----
  bf16x8 qf[4];
  { const unsigned short* qr = qg + (size_t)(rh*16 + l15)*DH + quad*8;
    #pragma unroll
    for (int kd = 0; kd < 4; kd++) qf[kd] = *(const bf16x8*)(qr + kd*32); }

  const int row0 = rh*16 + quad*4;
  const int* mgR[4]; float* attR[4];
  #pragma unroll
  for (int r = 0; r < 4; r++) {
    mgR[r]  = mg   + (size_t)(row0 + r)*NK + nh*32 + l15;
    attR[r] = attg + (size_t)(row0 + r)*NK + nh*32 + l15;
  }

  // swizzled byte-base offsets: addr = base ^ cb (cb 16B-aligned, < row size)
  const int kr0 = nh*32 + l15, kr1 = kr0 + 16;
  const int kbs0 = (kr0 << 8) ^ ((kr0 & 7) << 4);
  const int kbs1 = (kr1 << 8) ^ ((kr1 & 7) << 4);
  const int pr  = rh*16 + l15;
  const int pbs = (pr << 7) ^ ((pr & 7) << 4);
  int vbs[4];
  #pragma unroll
  for (int dt = 0; dt < 4; dt++) {
    int d = nh*64 + dt*16 + l15;
    vbs[dt] = (d << 7) ^ ((d & 7) << 4);
  }

  // stage 64x128-ush K tile (16KB). LDS linear; SOURCE pre-swizzled so that
  // LDS[row*256 + (cb ^ ((row&7)<<4))] = K[row][cb/2]  (rule 21: both-sides).
  auto stageK = [&](unsigned short* buf, const unsigned short* src) {
    #pragma unroll
    for (int i = 0; i < 4; i++) {
      int L = (wave << 12) + (i << 10) + (lane << 4);   // lds byte offset
      int row = L >> 8;
      int cb  = (L & 255) ^ ((row & 7) << 4);
      gl_lds16(src + ((size_t)row << 7) + (cb >> 1), buf + (L >> 1));
    }
  };
  // stage 128x64-ush Vt tile (16KB), same swizzle per 128B row
  auto stageV = [&](const unsigned short* src) {   // src = vg + k0
    #pragma unroll
    for (int i = 0; i < 4; i++) {
      int L = (wave << 12) + (i << 10) + (lane << 4);
      int d  = L >> 7;
      int cb = (L & 127) ^ ((d & 7) << 4);
      gl_lds16(src + (size_t)d*NK + (cb >> 1), VA + (L >> 1));
    }
  };
  auto loadMask = [&](int k0, int* mr) {   // 8 nontemporal dword loads
    #pragma unroll
    for (int nt = 0; nt < 2; nt++)
      #pragma unroll
      for (int r = 0; r < 4; r++)
        mr[nt*4 + r] = __builtin_nontemporal_load(mgR[r] + k0 + nt*16);
  };
  auto qkt = [&](const unsigned short* buf, f32x4& s0v, f32x4& s1v) {
    s0v = 0; s1v = 0;
    const char* bc = (const char*)buf;
    __builtin_amdgcn_s_setprio(1);
    #pragma unroll
    for (int kd = 0; kd < 4; kd++) {
      int cb = (kd*32 + quad*8) << 1;
      bf16x8 b0 = *(const bf16x8*)(bc + (kbs0 ^ cb));
      bf16x8 b1 = *(const bf16x8*)(bc + (kbs1 ^ cb));
      s0v = __builtin_amdgcn_mfma_f32_16x16x32_bf16(qf[kd], b0, s0v, 0, 0, 0);
      s1v = __builtin_amdgcn_mfma_f32_16x16x32_bf16(qf[kd], b1, s1v, 0, 0, 0);
    }
    __builtin_amdgcn_s_setprio(0);
  };

  // 256-bit mask shift-queue: after 32 pushes, tile i's 8 bits sit at byte i.
  unsigned mw0=0,mw1=0,mw2=0,mw3=0,mw4=0,mw5=0,mw6=0,mw7=0;
  float ls[4] = {0.f, 0.f, 0.f, 0.f};

  auto epi1 = [&](const int* mr, const f32x4& s0v, const f32x4& s1v) {
    unsigned nb = 0;
    #pragma unroll
    for (int nt = 0; nt < 2; nt++) {
      const f32x4& sv = nt ? s1v : s0v;
      #pragma unroll
      for (int r = 0; r < 4; r++) {
        float e = __expf(sv[r]*INV);
        if (mr[nt*4 + r] != 0) { nb |= 1u << (nt*4 + r); e = 0.f; }
        ls[r] += e;
      }
    }
    mw0=(mw0>>8)|(mw1<<24); mw1=(mw1>>8)|(mw2<<24); mw2=(mw2>>8)|(mw3<<24);
    mw3=(mw3>>8)|(mw4<<24); mw4=(mw4>>8)|(mw5<<24); mw5=(mw5>>8)|(mw6<<24);
    mw6=(mw6>>8)|(mw7<<24); mw7=(mw7>>8)|(nb<<24);
  };

  // ================= sweep 1: row sumexp + mask bit capture =================
  // K double-buffered across KA/VA. Per wave per tile: 4 stage + 8 mask = 12
  // vmem ops; vmcnt(12) keeps the NEXT tile's loads in flight across barriers.
  int mrA[8], mrB[8];
  stageK(KA, kg);
  loadMask(0, mrA);

  for (int t2 = 0; t2 < 32; t2 += 2) {
    __builtin_amdgcn_s_barrier();            // VA readers (tile t2-1) done
    asm volatile("" ::: "memory");
    stageK(VA, kg + (size_t)(t2+1)*64*DH);
    loadMask((t2+1)*64, mrB);
    asm volatile("s_waitcnt vmcnt(12)" ::: "memory");   // tile t2 complete
    __builtin_amdgcn_s_barrier();            // all waves have tile t2
    asm volatile("" ::: "memory");
    { f32x4 s0, s1; qkt(KA, s0, s1); epi1(mrA, s0, s1); }

    __builtin_amdgcn_s_barrier();            // KA readers done
    asm volatile("" ::: "memory");
    if (t2 + 2 < 32) {
      stageK(KA, kg + (size_t)(t2+2)*64*DH);
      loadMask((t2+2)*64, mrA);
      asm volatile("s_waitcnt vmcnt(12)" ::: "memory");
    } else {
      asm volatile("s_waitcnt vmcnt(0)" ::: "memory");
    }
    __builtin_amdgcn_s_barrier();
    asm volatile("" ::: "memory");
    { f32x4 s0, s1; qkt(VA, s0, s1); epi1(mrB, s0, s1); }
  }

  // ================= row-sum reduction ======================================
  __syncthreads();
  #pragma unroll
  for (int r = 0; r < 4; r++) atomicAdd(&Lrow[row0 + r], ls[r]);
  __syncthreads();
  float il[4];
  #pragma unroll
  for (int r = 0; r < 4; r++) il[r] = 1.0f / Lrow[row0 + r];

  f32x4 ca[4];
  #pragma unroll
  for (int dt = 0; dt < 4; dt++) ca[dt] = 0;

  // ================= sweep 2: att + ctx =====================================
  // K(t+1) staged during PV(t); V(t) staged during QK^T(t). Counted vmcnt:
  // at top: inflight = [att stores 8][K 4] + issue V4 -> vmcnt(4) = K done.
  // after epi: inflight = [V 4][att stores 8] -> vmcnt(8) = V done.
  stageK(KA, kg);
  for (int tt = 0; tt < 32; tt++) {
    __builtin_amdgcn_s_barrier();            // PV(tt-1) done -> VA writable
    asm volatile("" ::: "memory");
    stageV(vg + tt*64);
    asm volatile("s_waitcnt vmcnt(4)" ::: "memory");    // K(tt) in LDS
    __builtin_amdgcn_s_barrier();
    asm volatile("" ::: "memory");
    f32x4 s0, s1;
    qkt(KA, s0, s1);

    unsigned nb = mw0 & 255u;
    mw0=(mw0>>8)|(mw1<<24); mw1=(mw1>>8)|(mw2<<24); mw2=(mw2>>8)|(mw3<<24);
    mw3=(mw3>>8)|(mw4<<24); mw4=(mw4>>8)|(mw5<<24); mw5=(mw5>>8)|(mw6<<24);
    mw6=(mw6>>8)|(mw7<<24); mw7>>=8;
    #pragma unroll
    for (int nt = 0; nt < 2; nt++) {
      const f32x4& sv = nt ? s1 : s0;
      #pragma unroll
      for (int r = 0; r < 4; r++) {
        float e = __expf(sv[r]*INV) * il[r];
        if ((nb >> (nt*4 + r)) & 1) e = 0.f;
        __builtin_nontemporal_store(e, attR[r] + tt*64 + nt*16);
        int row = row0 + r;
        int cbw = ((nh*32 + nt*16 + l15) << 1) ^ ((row & 7) << 4);
        *(unsigned short*)((char*)Ps + (row << 7) + cbw) = f2b(e);
      }
    }
    asm volatile("s_waitcnt vmcnt(8) lgkmcnt(0)" ::: "memory");  // V done, Ps flushed
    __builtin_amdgcn_s_barrier();            // Ps visible to all waves
    asm volatile("" ::: "memory");
    if (tt + 1 < 32) stageK(KA, kg + (size_t)(tt+1)*64*DH);  // hides under PV

    __builtin_amdgcn_s_setprio(1);
    #pragma unroll
    for (int kv = 0; kv < 2; kv++) {
      int cb = (kv*32 + quad*8) << 1;
      bf16x8 pa = *(const bf16x8*)((const char*)Ps + (pbs ^ cb));
      #pragma unroll
      for (int dt = 0; dt < 4; dt++) {
        bf16x8 vb = *(const bf16x8*)((const char*)VA + (vbs[dt] ^ cb));
        ca[dt] = __builtin_amdgcn_mfma_f32_16x16x32_bf16(pa, vb, ca[dt], 0, 0, 0);
      }
    }
    __builtin_amdgcn_s_setprio(0);
  }

  #pragma unroll
  for (int dt = 0; dt < 4; dt++)
    #pragma unroll
    for (int r = 0; r < 4; r++)
      cg[(size_t)(row0 + r)*DH + nh*64 + dt*16 + l15] = ca[dt][r];
}

extern "C" void kernel_launch(void* const* d_in, const int* in_sizes, int n_in,
                              void* d_out, int out_size, void* d_ws, size_t ws_size,
                              hipStream_t stream) {
  const float* q = (const float*)d_in[0];
  const float* k = (const float*)d_in[1];
  const float* v = (const float*)d_in[2];
  const int* mask = (const int*)d_in[3];
  float* ctx = (float*)d_out;
  float* att = ctx + (size_t)B_*NQ*DH;

  const size_t NE = (size_t)B_*NQ*DH;
  unsigned short* qws = (unsigned short*)d_ws;
  unsigned short* kws = qws + NE;
  unsigned short* vws = kws + NE;

  k_cvt  <<<(int)(NE/1024), 256, 0, stream>>>(q, qws, (int)(NE/4));
  k_cvt  <<<(int)(NE/1024), 256, 0, stream>>>(k, kws, (int)(NE/4));
  k_trans<<<dim3(NK/32, DH/32, B_), 256, 0, stream>>>(v, vws);
  k_attn <<<dim3(NQ/32, B_), 256, 0, stream>>>(qws, kws, vws, mask, att, ctx);
}